// Round 1
// baseline (159.703 us; speedup 1.0000x reference)
//
#include <hip/hip_runtime.h>
#include <math.h>

#define B 32768
#define S 256
#define H1 10
#define H2 6
#define NB 512               // blocks in kernel 1
#define CHUNK (B / NB)       // batch rows per block = 64
#define L2_SMOOTH 1e-3f
#define EPS 1e-10f

// tanh via fast exp: tanh(x) = (e^{2x}-1)/(e^{2x}+1), clamped to avoid inf/inf
__device__ __forceinline__ float fast_tanh(float x) {
    x = fminf(fmaxf(x, -15.0f), 15.0f);
    float e = __expf(2.0f * x);
    return (e - 1.0f) / (e + 1.0f);
}

// Kernel 1: fused MLP forward + analytic d2out/dx2, per-block partial sums.
// thread t handles subnet s = t; block b handles batch rows [b*CHUNK, (b+1)*CHUNK)
__global__ __launch_bounds__(256) void k1_mlp(
    const float* __restrict__ x,
    const float* __restrict__ W1, const float* __restrict__ b1,
    const float* __restrict__ W2, const float* __restrict__ b2,
    const float* __restrict__ W3, const float* __restrict__ b3,
    float* __restrict__ out,          // [B][S] unnormalized, written into d_out
    float* __restrict__ psum,         // [NB][S]
    float* __restrict__ psum2,        // [NB][S]
    float* __restrict__ pg2)          // [NB][S]
{
    const int s   = threadIdx.x;
    const int blk = blockIdx.x;

    // per-subnet params in registers (93 floats, statically indexed)
    float w1[H1], bb1[H1], w2[H1][H2], bb2[H2], w3[H2], bb3;
#pragma unroll
    for (int i = 0; i < H1; ++i) { w1[i] = W1[s * H1 + i]; bb1[i] = b1[s * H1 + i]; }
#pragma unroll
    for (int i = 0; i < H1; ++i)
#pragma unroll
        for (int j = 0; j < H2; ++j) w2[i][j] = W2[(s * H1 + i) * H2 + j];
#pragma unroll
    for (int j = 0; j < H2; ++j) { bb2[j] = b2[s * H2 + j]; w3[j] = W3[s * H2 + j]; }
    bb3 = b3[s];

    float so = 0.0f, so2 = 0.0f, sg2 = 0.0f;
    const int b0 = blk * CHUNK;

    for (int bi = 0; bi < CHUNK; ++bi) {
        const int b = b0 + bi;
        const float xs = x[b * S + s];          // coalesced across threads

        float v[H2], vp[H2], vpp[H2];
#pragma unroll
        for (int j = 0; j < H2; ++j) { v[j] = bb2[j]; vp[j] = 0.0f; vpp[j] = 0.0f; }

#pragma unroll
        for (int i = 0; i < H1; ++i) {
            const float h   = fast_tanh(fmaf(xs, w1[i], bb1[i]));
            const float t   = 1.0f - h * h;
            const float hp  = t * w1[i];                  // dh/dx
            const float hpp = -2.0f * h * hp * w1[i];     // d2h/dx2
#pragma unroll
            for (int j = 0; j < H2; ++j) {
                v[j]   = fmaf(h,   w2[i][j], v[j]);
                vp[j]  = fmaf(hp,  w2[i][j], vp[j]);
                vpp[j] = fmaf(hpp, w2[i][j], vpp[j]);
            }
        }

        float o = bb3, g2 = 0.0f;
#pragma unroll
        for (int j = 0; j < H2; ++j) {
            const float g   = fast_tanh(v[j]);
            const float tg  = 1.0f - g * g;
            const float gpp = tg * (vpp[j] - 2.0f * g * vp[j] * vp[j]);
            o  = fmaf(g,     w3[j], o);
            g2 = fmaf(w3[j], gpp,   g2);
        }

        out[b * S + s] = o;                      // coalesced
        so  += o;
        so2  = fmaf(o,  o,  so2);
        sg2  = fmaf(g2, g2, sg2);
    }

    psum [blk * S + s] = so;
    psum2[blk * S + s] = so2;
    pg2  [blk * S + s] = sg2;
}

// Kernel 2: per-subnet reduction of NB partials -> mean, 1/std, smooth term
__global__ __launch_bounds__(256) void k2_reduce(
    const float* __restrict__ psum, const float* __restrict__ psum2,
    const float* __restrict__ pg2,
    float* __restrict__ mean_arr, float* __restrict__ rstd_arr,
    float* __restrict__ smooth_arr)
{
    const int s = blockIdx.x;   // subnet
    const int t = threadIdx.x;

    float a = 0.0f, b_ = 0.0f, c = 0.0f;
    for (int k = t; k < NB; k += 256) {
        a  += psum [k * S + s];
        b_ += psum2[k * S + s];
        c  += pg2  [k * S + s];
    }

    __shared__ float sa[256], sb[256], sc[256];
    sa[t] = a; sb[t] = b_; sc[t] = c;
    __syncthreads();
    for (int st = 128; st > 0; st >>= 1) {
        if (t < st) { sa[t] += sa[t + st]; sb[t] += sb[t + st]; sc[t] += sc[t + st]; }
        __syncthreads();
    }

    if (t == 0) {
        const float inv_b = 1.0f / (float)B;
        const float mean  = sa[0] * inv_b;
        float var = sb[0] * inv_b - mean * mean;
        var = fmaxf(var, 0.0f);
        const float stdv = fmaxf(sqrtf(var), EPS);
        const float rstd = 1.0f / stdv;
        mean_arr[s]   = mean;
        rstd_arr[s]   = rstd;
        smooth_arr[s] = (sc[0] * inv_b) * rstd;   // mean(g2^2)/std
    }
}

// Kernel 3: normalize d_out in place (float4), plus one block for the loss sum
#define K3_NORM_BLOCKS (B * S / (256 * 4))   // 8192
__global__ __launch_bounds__(256) void k3_norm(
    float* __restrict__ out,
    const float* __restrict__ mean_arr, const float* __restrict__ rstd_arr,
    const float* __restrict__ smooth_arr)
{
    if ((int)blockIdx.x == K3_NORM_BLOCKS) {
        // loss reduction over S=256 subnets
        const int t = threadIdx.x;
        __shared__ float sa[256];
        sa[t] = smooth_arr[t];
        __syncthreads();
        for (int st = 128; st > 0; st >>= 1) {
            if (t < st) sa[t] += sa[t + st];
            __syncthreads();
        }
        if (t == 0) out[B * S] = L2_SMOOTH * sa[0];
        return;
    }

    const int i4   = (int)blockIdx.x * 256 + (int)threadIdx.x;
    const int base = i4 * 4;                 // multiple of 4; S=256 -> no wrap
    float4 v = *reinterpret_cast<float4*>(&out[base]);
    const int s0 = base & (S - 1);
    v.x = (v.x - mean_arr[s0 + 0]) * rstd_arr[s0 + 0];
    v.y = (v.y - mean_arr[s0 + 1]) * rstd_arr[s0 + 1];
    v.z = (v.z - mean_arr[s0 + 2]) * rstd_arr[s0 + 2];
    v.w = (v.w - mean_arr[s0 + 3]) * rstd_arr[s0 + 3];
    *reinterpret_cast<float4*>(&out[base]) = v;
}

extern "C" void kernel_launch(void* const* d_in, const int* in_sizes, int n_in,
                              void* d_out, int out_size, void* d_ws, size_t ws_size,
                              hipStream_t stream) {
    const float* x  = (const float*)d_in[0];
    const float* W1 = (const float*)d_in[1];
    const float* b1 = (const float*)d_in[2];
    const float* W2 = (const float*)d_in[3];
    const float* b2 = (const float*)d_in[4];
    const float* W3 = (const float*)d_in[5];
    const float* b3 = (const float*)d_in[6];
    float* out = (float*)d_out;

    // workspace layout (floats): psum[NB*S] | psum2[NB*S] | pg2[NB*S] | mean[S] | rstd[S] | smooth[S]
    float* psum   = (float*)d_ws;
    float* psum2  = psum  + NB * S;
    float* pg2    = psum2 + NB * S;
    float* meanA  = pg2   + NB * S;
    float* rstdA  = meanA + S;
    float* smooth = rstdA + S;

    k1_mlp<<<NB, 256, 0, stream>>>(x, W1, b1, W2, b2, W3, b3, out, psum, psum2, pg2);
    k2_reduce<<<S, 256, 0, stream>>>(psum, psum2, pg2, meanA, rstdA, smooth);
    k3_norm<<<K3_NORM_BLOCKS + 1, 256, 0, stream>>>(out, meanA, rstdA, smooth);
}

// Round 3
// 121.398 us; speedup vs baseline: 1.3155x; 1.3155x over previous
//
#include <hip/hip_runtime.h>
#include <math.h>

#define B 32768
#define S 256
#define H1 10
#define H2 6
#define NB 1024              // blocks in kernel 1
#define L2_SMOOTH 1e-3f
#define EPS 1e-10f

// Divide-free tanh + sech^2:
//   e = 2^(x * 2*log2 e) = e^{2x};  r = 1/(e+1)
//   tanh(x)  = 1 - 2r
//   sech2(x) = 1 - tanh^2 = 4 r (1 - r)
// Saturation is exact: x>>0 -> e=inf, r=0, th=1, s2=0; x<<0 -> e=0, r=1, th=-1, s2=0.
__device__ __forceinline__ void tanh_pair(float x, float& th, float& s2) {
    const float e = __builtin_amdgcn_exp2f(x * 2.885390081777927f);
    const float r = __builtin_amdgcn_rcpf(e + 1.0f);
    th = fmaf(-2.0f, r, 1.0f);
    s2 = (4.0f * r) * (1.0f - r);
}

// Kernel 1: fused MLP forward + analytic d2out/dx2, per-block partial sums.
// thread t = subnet s; block handles batch rows [blk*CHUNK, (blk+1)*CHUNK)
__global__ __launch_bounds__(256, 3) void k1_mlp(
    const float* __restrict__ x,
    const float* __restrict__ W1, const float* __restrict__ b1,
    const float* __restrict__ W2, const float* __restrict__ b2,
    const float* __restrict__ W3, const float* __restrict__ b3,
    float* __restrict__ out,          // [B][S] unnormalized (d_out)
    float* __restrict__ psum,         // [NB][S]
    float* __restrict__ psum2,        // [NB][S]
    float* __restrict__ pg2)          // [NB][S]
{
    const int s   = threadIdx.x;
    const int blk = blockIdx.x;
    const int CHUNK = B / NB;

    // per-subnet params in registers (93 floats, statically indexed)
    float w1[H1], bb1[H1], w2[H1][H2], bb2[H2], w3[H2], bb3;
#pragma unroll
    for (int i = 0; i < H1; ++i) { w1[i] = W1[s * H1 + i]; bb1[i] = b1[s * H1 + i]; }
#pragma unroll
    for (int i = 0; i < H1; ++i)
#pragma unroll
        for (int j = 0; j < H2; ++j) w2[i][j] = W2[(s * H1 + i) * H2 + j];
#pragma unroll
    for (int j = 0; j < H2; ++j) { bb2[j] = b2[s * H2 + j]; w3[j] = W3[s * H2 + j]; }
    bb3 = b3[s];

    float so = 0.0f, so2 = 0.0f, sg2 = 0.0f;
    const int b0 = blk * CHUNK;

    for (int bi = 0; bi < CHUNK; ++bi) {
        const int b = b0 + bi;
        const float xs = x[b * S + s];          // coalesced across threads

        float v[H2], vp[H2], vpp[H2];
#pragma unroll
        for (int j = 0; j < H2; ++j) { v[j] = bb2[j]; vp[j] = 0.0f; vpp[j] = 0.0f; }

#pragma unroll
        for (int i = 0; i < H1; ++i) {
            float h, t;
            tanh_pair(fmaf(xs, w1[i], bb1[i]), h, t);
            const float hp  = t * w1[i];                  // dh/dx
            const float hpp = -2.0f * (h * hp) * w1[i];   // d2h/dx2
#pragma unroll
            for (int j = 0; j < H2; ++j) {
                v[j]   = fmaf(h,   w2[i][j], v[j]);
                vp[j]  = fmaf(hp,  w2[i][j], vp[j]);
                vpp[j] = fmaf(hpp, w2[i][j], vpp[j]);
            }
        }

        float o = bb3, g2 = 0.0f;
#pragma unroll
        for (int j = 0; j < H2; ++j) {
            float g, tg;
            tanh_pair(v[j], g, tg);
            const float c   = -2.0f * (g * vp[j]);
            const float gpp = tg * fmaf(c, vp[j], vpp[j]);
            o  = fmaf(g,     w3[j], o);
            g2 = fmaf(w3[j], gpp,   g2);
        }

        out[b * S + s] = o;                      // coalesced
        so  += o;
        so2  = fmaf(o,  o,  so2);
        sg2  = fmaf(g2, g2, sg2);
    }

    psum [blk * S + s] = so;
    psum2[blk * S + s] = so2;
    pg2  [blk * S + s] = sg2;
}

// Kernel 2: per-subnet reduction of NB partials -> mean, 1/std, smooth term
__global__ __launch_bounds__(256) void k2_reduce(
    const float* __restrict__ psum, const float* __restrict__ psum2,
    const float* __restrict__ pg2,
    float* __restrict__ mean_arr, float* __restrict__ rstd_arr,
    float* __restrict__ smooth_arr, int nb)
{
    const int s = blockIdx.x;   // subnet
    const int t = threadIdx.x;

    float a = 0.0f, b_ = 0.0f, c = 0.0f;
    for (int k = t; k < nb; k += 256) {
        a  += psum [k * S + s];
        b_ += psum2[k * S + s];
        c  += pg2  [k * S + s];
    }

    __shared__ float sa[256], sb[256], sc[256];
    sa[t] = a; sb[t] = b_; sc[t] = c;
    __syncthreads();
    for (int st = 128; st > 0; st >>= 1) {
        if (t < st) { sa[t] += sa[t + st]; sb[t] += sb[t + st]; sc[t] += sc[t + st]; }
        __syncthreads();
    }

    if (t == 0) {
        const float inv_b = 1.0f / (float)B;
        const float mean  = sa[0] * inv_b;
        float var = sb[0] * inv_b - mean * mean;
        var = fmaxf(var, 0.0f);
        const float stdv = fmaxf(sqrtf(var), EPS);
        const float rstd = 1.0f / stdv;
        mean_arr[s]   = mean;
        rstd_arr[s]   = rstd;
        smooth_arr[s] = (sc[0] * inv_b) * rstd;   // mean(g2^2)/std
    }
}

// Kernel 3: normalize d_out in place (float4), plus one block for the loss sum
#define K3_NORM_BLOCKS (B * S / (256 * 4))   // 8192
__global__ __launch_bounds__(256) void k3_norm(
    float* __restrict__ out,
    const float* __restrict__ mean_arr, const float* __restrict__ rstd_arr,
    const float* __restrict__ smooth_arr)
{
    if ((int)blockIdx.x == K3_NORM_BLOCKS) {
        const int t = threadIdx.x;
        __shared__ float sa[256];
        sa[t] = smooth_arr[t];
        __syncthreads();
        for (int st = 128; st > 0; st >>= 1) {
            if (t < st) sa[t] += sa[t + st];
            __syncthreads();
        }
        if (t == 0) out[B * S] = L2_SMOOTH * sa[0];
        return;
    }

    const int i4   = (int)blockIdx.x * 256 + (int)threadIdx.x;
    const int base = i4 * 4;                 // multiple of 4; S=256 -> no wrap
    float4 v = *reinterpret_cast<float4*>(&out[base]);
    const int s0 = base & (S - 1);
    v.x = (v.x - mean_arr[s0 + 0]) * rstd_arr[s0 + 0];
    v.y = (v.y - mean_arr[s0 + 1]) * rstd_arr[s0 + 1];
    v.z = (v.z - mean_arr[s0 + 2]) * rstd_arr[s0 + 2];
    v.w = (v.w - mean_arr[s0 + 3]) * rstd_arr[s0 + 3];
    *reinterpret_cast<float4*>(&out[base]) = v;
}

extern "C" void kernel_launch(void* const* d_in, const int* in_sizes, int n_in,
                              void* d_out, int out_size, void* d_ws, size_t ws_size,
                              hipStream_t stream) {
    const float* x  = (const float*)d_in[0];
    const float* W1 = (const float*)d_in[1];
    const float* b1 = (const float*)d_in[2];
    const float* W2 = (const float*)d_in[3];
    const float* b2 = (const float*)d_in[4];
    const float* W3 = (const float*)d_in[5];
    const float* b3 = (const float*)d_in[6];
    float* out = (float*)d_out;

    // workspace (floats): psum[NB*S] | psum2[NB*S] | pg2[NB*S] | mean[S] | rstd[S] | smooth[S]
    float* psum   = (float*)d_ws;
    float* psum2  = psum  + NB * S;
    float* pg2    = psum2 + NB * S;
    float* meanA  = pg2   + NB * S;
    float* rstdA  = meanA + S;
    float* smooth = rstdA + S;

    k1_mlp<<<NB, 256, 0, stream>>>(x, W1, b1, W2, b2, W3, b3, out, psum, psum2, pg2);
    k2_reduce<<<S, 256, 0, stream>>>(psum, psum2, pg2, meanA, rstdA, smooth, NB);
    k3_norm<<<K3_NORM_BLOCKS + 1, 256, 0, stream>>>(out, meanA, rstdA, smooth);
}

// Round 4
// 120.280 us; speedup vs baseline: 1.3278x; 1.0093x over previous
//
#include <hip/hip_runtime.h>
#include <math.h>

#define B 32768
#define S 256
#define H1 10
#define H2 6
#define ST 16            // subnets per block = waves per block
#define CB 1024          // batch rows per block
#define RB 256           // batch rows per LDS tile round
#define PAD 20           // LDS row pitch in floats (16 data + 4 pad, keeps float4 16B-aligned)
#define NCHUNK (B / CB)  // 32 batch chunks
#define L2_SMOOTH 1e-3f
#define EPS 1e-10f

// force a wave-uniform float into an SGPR
__device__ __forceinline__ float rfl(float x) {
    return __int_as_float(__builtin_amdgcn_readfirstlane(__float_as_int(x)));
}

// Divide-free tanh + sech^2 (exact saturation through rcp(inf)=0):
//   e = e^{2x}; r = 1/(e+1); tanh = 1-2r; sech^2 = 4r(1-r)
__device__ __forceinline__ void tanh_pair(float x, float& th, float& s2) {
    const float e = __builtin_amdgcn_exp2f(x * 2.885390081777927f);
    const float r = __builtin_amdgcn_rcpf(e + 1.0f);
    th = fmaf(-2.0f, r, 1.0f);
    s2 = (4.0f * r) * (1.0f - r);
}

// K1: wave = one subnet, lane = batch element. Weights wave-uniform (SGPR).
// x gathered via LDS-tiled transpose; o scattered back the same way.
__global__ __launch_bounds__(1024, 4) void k1_mlp(
    const float* __restrict__ x,
    const float* __restrict__ W1, const float* __restrict__ b1,
    const float* __restrict__ W2, const float* __restrict__ b2,
    const float* __restrict__ W3, const float* __restrict__ b3,
    float* __restrict__ out,          // [B][S] unnormalized (d_out)
    float* __restrict__ psum,         // [S][NCHUNK]
    float* __restrict__ psum2,        // [S][NCHUNK]
    float* __restrict__ pg2)          // [S][NCHUNK]
{
    __shared__ float xlds[RB * PAD];
    __shared__ float olds[RB * PAD];

    const int t  = threadIdx.x;
    const int wv = __builtin_amdgcn_readfirstlane(t >> 6);   // wave id 0..15, uniform
    const int l  = t & 63;                                   // lane
    const int s0 = blockIdx.x * ST;                          // block's first subnet
    const int s  = s0 + wv;                                  // this wave's subnet
    const int bbase = blockIdx.y * CB;

    // --- wave-uniform weights; W2/w3/b2/b3 pinned to SGPR via readfirstlane ---
    float w1[H1], bb1[H1], w2s[H1][H2], bb2[H2], w3[H2];
#pragma unroll
    for (int i = 0; i < H1; ++i) { w1[i] = W1[s * H1 + i]; bb1[i] = b1[s * H1 + i]; }
#pragma unroll
    for (int i = 0; i < H1; ++i)
#pragma unroll
        for (int j = 0; j < H2; ++j) w2s[i][j] = rfl(W2[(s * H1 + i) * H2 + j]);
#pragma unroll
    for (int j = 0; j < H2; ++j) { bb2[j] = rfl(b2[s * H2 + j]); w3[j] = rfl(W3[s * H2 + j]); }
    const float bb3 = rfl(b3[s]);
    float w1m2[H1];                       // -2*w1^2 (for h'' = h*sech2 * (-2 w1^2))
#pragma unroll
    for (int i = 0; i < H1; ++i) w1m2[i] = -2.0f * w1[i] * w1[i];

    const int brow = t >> 2;              // 0..255: coop-load row
    const int s4   = (t & 3) * 4;         // 0,4,8,12: coop-load col group

    float so = 0.0f, so2 = 0.0f, sg2 = 0.0f;

    for (int r = 0; r < CB / RB; ++r) {
        // cooperative x-tile load: [RB rows][ST cols], float4 per thread
        const float4 xv = *reinterpret_cast<const float4*>(
            &x[(bbase + r * RB + brow) * S + s0 + s4]);
        *reinterpret_cast<float4*>(&xlds[brow * PAD + s4]) = xv;
        __syncthreads();                  // tile ready (also: prev round's olds reads done)

#pragma unroll
        for (int k = 0; k < RB / 64; ++k) {
            const float xs = xlds[(k * 64 + l) * PAD + wv];

            float v[H2], vp[H2], vpp[H2];
#pragma unroll
            for (int j = 0; j < H2; ++j) { v[j] = bb2[j]; vp[j] = 0.0f; vpp[j] = 0.0f; }

#pragma unroll
            for (int i = 0; i < H1; ++i) {
                float h, tt;
                tanh_pair(fmaf(xs, w1[i], bb1[i]), h, tt);
                const float hp  = tt * w1[i];
                const float hpp = (h * tt) * w1m2[i];
#pragma unroll
                for (int j = 0; j < H2; ++j) {
                    v[j]   = fmaf(h,   w2s[i][j], v[j]);
                    vp[j]  = fmaf(hp,  w2s[i][j], vp[j]);
                    vpp[j] = fmaf(hpp, w2s[i][j], vpp[j]);
                }
            }

            float o = bb3, g2 = 0.0f;
#pragma unroll
            for (int j = 0; j < H2; ++j) {
                float g, tg;
                tanh_pair(v[j], g, tg);
                const float c   = -2.0f * (g * vp[j]);
                const float gpp = tg * fmaf(c, vp[j], vpp[j]);
                o  = fmaf(g,     w3[j], o);
                g2 = fmaf(w3[j], gpp,   g2);
            }

            olds[(k * 64 + l) * PAD + wv] = o;
            so += o; so2 = fmaf(o, o, so2); sg2 = fmaf(g2, g2, sg2);
        }
        __syncthreads();                  // olds complete; xlds reads complete

        // cooperative o-tile store (transpose back to [B][S])
        const float4 ov = *reinterpret_cast<const float4*>(&olds[brow * PAD + s4]);
        *reinterpret_cast<float4*>(&out[(bbase + r * RB + brow) * S + s0 + s4]) = ov;
    }

    // deterministic in-wave butterfly reduction of the 3 partials
#pragma unroll
    for (int m = 1; m < 64; m <<= 1) {
        so  += __shfl_xor(so,  m, 64);
        so2 += __shfl_xor(so2, m, 64);
        sg2 += __shfl_xor(sg2, m, 64);
    }
    if (l == 0) {
        psum [s * NCHUNK + blockIdx.y] = so;
        psum2[s * NCHUNK + blockIdx.y] = so2;
        pg2  [s * NCHUNK + blockIdx.y] = sg2;
    }
}

// K2: per-subnet reduction of NCHUNK partials -> mean, 1/std, smooth term
__global__ __launch_bounds__(256) void k2_reduce(
    const float* __restrict__ psum, const float* __restrict__ psum2,
    const float* __restrict__ pg2,
    float* __restrict__ mean_arr, float* __restrict__ rstd_arr,
    float* __restrict__ smooth_arr)
{
    const int s = blockIdx.x;
    const int t = threadIdx.x;

    float a = 0.0f, b_ = 0.0f, c = 0.0f;
    if (t < NCHUNK) {
        a  = psum [s * NCHUNK + t];
        b_ = psum2[s * NCHUNK + t];
        c  = pg2  [s * NCHUNK + t];
    }

    __shared__ float sa[256], sb[256], sc[256];
    sa[t] = a; sb[t] = b_; sc[t] = c;
    __syncthreads();
    for (int st = 128; st > 0; st >>= 1) {
        if (t < st) { sa[t] += sa[t + st]; sb[t] += sb[t + st]; sc[t] += sc[t + st]; }
        __syncthreads();
    }

    if (t == 0) {
        const float inv_b = 1.0f / (float)B;
        const float mean  = sa[0] * inv_b;
        float var = sb[0] * inv_b - mean * mean;
        var = fmaxf(var, 0.0f);
        const float stdv = fmaxf(sqrtf(var), EPS);
        const float rstd = 1.0f / stdv;
        mean_arr[s]   = mean;
        rstd_arr[s]   = rstd;
        smooth_arr[s] = (sc[0] * inv_b) * rstd;   // mean(g2^2)/std
    }
}

// K3: normalize d_out in place (float4), plus one block for the loss sum
#define K3_NORM_BLOCKS (B * S / (256 * 4))   // 8192
__global__ __launch_bounds__(256) void k3_norm(
    float* __restrict__ out,
    const float* __restrict__ mean_arr, const float* __restrict__ rstd_arr,
    const float* __restrict__ smooth_arr)
{
    if ((int)blockIdx.x == K3_NORM_BLOCKS) {
        const int t = threadIdx.x;
        __shared__ float sa[256];
        sa[t] = smooth_arr[t];
        __syncthreads();
        for (int st = 128; st > 0; st >>= 1) {
            if (t < st) sa[t] += sa[t + st];
            __syncthreads();
        }
        if (t == 0) out[B * S] = L2_SMOOTH * sa[0];
        return;
    }

    const int i4   = (int)blockIdx.x * 256 + (int)threadIdx.x;
    const int base = i4 * 4;
    float4 v = *reinterpret_cast<float4*>(&out[base]);
    const int s0 = base & (S - 1);
    v.x = (v.x - mean_arr[s0 + 0]) * rstd_arr[s0 + 0];
    v.y = (v.y - mean_arr[s0 + 1]) * rstd_arr[s0 + 1];
    v.z = (v.z - mean_arr[s0 + 2]) * rstd_arr[s0 + 2];
    v.w = (v.w - mean_arr[s0 + 3]) * rstd_arr[s0 + 3];
    *reinterpret_cast<float4*>(&out[base]) = v;
}

extern "C" void kernel_launch(void* const* d_in, const int* in_sizes, int n_in,
                              void* d_out, int out_size, void* d_ws, size_t ws_size,
                              hipStream_t stream) {
    const float* x  = (const float*)d_in[0];
    const float* W1 = (const float*)d_in[1];
    const float* b1 = (const float*)d_in[2];
    const float* W2 = (const float*)d_in[3];
    const float* b2 = (const float*)d_in[4];
    const float* W3 = (const float*)d_in[5];
    const float* b3 = (const float*)d_in[6];
    float* out = (float*)d_out;

    // workspace (floats): psum[S*NCHUNK] | psum2[S*NCHUNK] | pg2[S*NCHUNK] | mean[S] | rstd[S] | smooth[S]
    float* psum   = (float*)d_ws;
    float* psum2  = psum  + S * NCHUNK;
    float* pg2    = psum2 + S * NCHUNK;
    float* meanA  = pg2   + S * NCHUNK;
    float* rstdA  = meanA + S;
    float* smooth = rstdA + S;

    k1_mlp<<<dim3(S / ST, NCHUNK), 1024, 0, stream>>>(
        x, W1, b1, W2, b2, W3, b3, out, psum, psum2, pg2);
    k2_reduce<<<S, 256, 0, stream>>>(psum, psum2, pg2, meanA, rstdA, smooth);
    k3_norm<<<K3_NORM_BLOCKS + 1, 256, 0, stream>>>(out, meanA, rstdA, smooth);
}

// Round 5
// 113.590 us; speedup vs baseline: 1.4060x; 1.0589x over previous
//
#include <hip/hip_runtime.h>
#include <math.h>

#define B 32768
#define S 256
#define H1 10
#define H2 6
#define ROWS 512                 // batch rows per wave
#define CH (B / ROWS)            // 64 chunks per subnet
#define WPB 4                    // waves per block
#define L2_SMOOTH 1e-3f
#define EPS 1e-10f

__device__ __forceinline__ int rfl_i(int x) { return __builtin_amdgcn_readfirstlane(x); }
__device__ __forceinline__ float rfl(float x) {
    return __int_as_float(__builtin_amdgcn_readfirstlane(__float_as_int(x)));
}

// Divide-free tanh + sech^2 (exact saturation through rcp(inf)=0):
//   e = e^{2x}; r = 1/(e+1); tanh = 1-2r; sech^2 = 4r(1-r)
__device__ __forceinline__ void tanh_pair(float x, float& th, float& s2) {
    const float e = __builtin_amdgcn_exp2f(x * 2.885390081777927f);
    const float r = __builtin_amdgcn_rcpf(e + 1.0f);
    th = fmaf(-2.0f, r, 1.0f);
    s2 = (4.0f * r) * (1.0f - r);
}

// K1: wave = one subnet, lane = batch row. No LDS, no barriers.
// x/out accessed at stride S*4B per lane (L1/L2-served; 64B line = 16 subnets,
// 4 adjacent-subnet waves per block reuse each line).
__global__ __launch_bounds__(256, 6) void k1_mlp(
    const float* __restrict__ x,
    const float* __restrict__ W1, const float* __restrict__ b1,
    const float* __restrict__ W2, const float* __restrict__ b2,
    const float* __restrict__ W3, const float* __restrict__ b3,
    float* __restrict__ out,          // [B][S] unnormalized (d_out)
    float* __restrict__ psum,         // [S][CH]
    float* __restrict__ psum2,        // [S][CH]
    float* __restrict__ pg2)          // [S][CH]
{
    const int t   = threadIdx.x;
    const int wid = blockIdx.x * WPB + rfl_i(t >> 6);
    const int l   = t & 63;
    const int s   = wid & (S - 1);    // subnet (adjacent waves -> adjacent subnets)
    const int c   = wid >> 8;         // batch chunk 0..CH-1   (S == 256)

    // --- wave-uniform weights: W2/w3 forced to SGPR; b2/b3 pinned to VGPR so
    //     init-fmas keep a single scalar operand; w1/b1 scalarized by compiler.
    float w1[H1], bb1[H1], m2w1[H1], w2s[H1][H2], bb2[H2], w3s[H2];
#pragma unroll
    for (int i = 0; i < H1; ++i) {
        w1[i]   = W1[s * H1 + i];
        bb1[i]  = b1[s * H1 + i];
        m2w1[i] = -2.0f * w1[i];
    }
#pragma unroll
    for (int i = 0; i < H1; ++i)
#pragma unroll
        for (int j = 0; j < H2; ++j) w2s[i][j] = rfl(W2[(s * H1 + i) * H2 + j]);
#pragma unroll
    for (int j = 0; j < H2; ++j) {
        bb2[j] = b2[s * H2 + j];
        asm("" : "+v"(bb2[j]));       // pin to VGPR (fma legality: 1 SGPR max)
        w3s[j] = rfl(W3[s * H2 + j]);
    }
    float bb3 = b3[s];
    asm("" : "+v"(bb3));

    const size_t base = (size_t)(c * ROWS) * S + s;
    const float* px = x   + base;
    float*       po = out + base;
    const int loff = l * S;           // fixed per-lane offset

    float so = 0.0f, so2 = 0.0f, sg2 = 0.0f;

    for (int k = 0; k < ROWS / 64; ++k) {
        const float xs = px[k * 64 * S + loff];

        float v[H2], vp[H2], vpp[H2];
        {   // i = 0 peeled: initializes v/vp/vpp without v_mov chains
            float h, tt;
            tanh_pair(fmaf(xs, w1[0], bb1[0]), h, tt);
            const float hp  = tt * w1[0];
            const float hpp = (h * hp) * m2w1[0];
#pragma unroll
            for (int j = 0; j < H2; ++j) {
                v[j]   = fmaf(h, w2s[0][j], bb2[j]);
                vp[j]  = hp  * w2s[0][j];
                vpp[j] = hpp * w2s[0][j];
            }
        }
#pragma unroll
        for (int i = 1; i < H1; ++i) {
            float h, tt;
            tanh_pair(fmaf(xs, w1[i], bb1[i]), h, tt);
            const float hp  = tt * w1[i];
            const float hpp = (h * hp) * m2w1[i];
#pragma unroll
            for (int j = 0; j < H2; ++j) {
                v[j]   = fmaf(h,   w2s[i][j], v[j]);
                vp[j]  = fmaf(hp,  w2s[i][j], vp[j]);
                vpp[j] = fmaf(hpp, w2s[i][j], vpp[j]);
            }
        }

        float o, g2;
        {   // j = 0 peeled
            float g, tg;
            tanh_pair(v[0], g, tg);
            const float c0  = -2.0f * (g * vp[0]);
            const float gpp = tg * fmaf(c0, vp[0], vpp[0]);
            o  = fmaf(g, w3s[0], bb3);
            g2 = gpp * w3s[0];
        }
#pragma unroll
        for (int j = 1; j < H2; ++j) {
            float g, tg;
            tanh_pair(v[j], g, tg);
            const float cj  = -2.0f * (g * vp[j]);
            const float gpp = tg * fmaf(cj, vp[j], vpp[j]);
            o  = fmaf(g,     w3s[j], o);
            g2 = fmaf(w3s[j], gpp,   g2);
        }

        po[k * 64 * S + loff] = o;
        so += o; so2 = fmaf(o, o, so2); sg2 = fmaf(g2, g2, sg2);
    }

    // deterministic in-wave butterfly reduction
#pragma unroll
    for (int m = 1; m < 64; m <<= 1) {
        so  += __shfl_xor(so,  m, 64);
        so2 += __shfl_xor(so2, m, 64);
        sg2 += __shfl_xor(sg2, m, 64);
    }
    if (l == 0) {
        psum [s * CH + c] = so;
        psum2[s * CH + c] = so2;
        pg2  [s * CH + c] = sg2;
    }
}

// K2: one wave per subnet reduces CH=64 partials -> mean, 1/std, smooth term
__global__ __launch_bounds__(64) void k2_reduce(
    const float* __restrict__ psum, const float* __restrict__ psum2,
    const float* __restrict__ pg2,
    float* __restrict__ mean_arr, float* __restrict__ rstd_arr,
    float* __restrict__ smooth_arr)
{
    const int s = blockIdx.x;
    const int l = threadIdx.x;       // 0..63 == CH

    float a  = psum [s * CH + l];
    float b_ = psum2[s * CH + l];
    float cc = pg2  [s * CH + l];
#pragma unroll
    for (int m = 1; m < 64; m <<= 1) {
        a  += __shfl_xor(a,  m, 64);
        b_ += __shfl_xor(b_, m, 64);
        cc += __shfl_xor(cc, m, 64);
    }
    if (l == 0) {
        const float inv_b = 1.0f / (float)B;
        const float mean  = a * inv_b;
        float var = b_ * inv_b - mean * mean;
        var = fmaxf(var, 0.0f);
        const float stdv = fmaxf(sqrtf(var), EPS);
        const float rstd = 1.0f / stdv;
        mean_arr[s]   = mean;
        rstd_arr[s]   = rstd;
        smooth_arr[s] = (cc * inv_b) * rstd;   // mean(g2^2)/std
    }
}

// K3: normalize d_out in place (float4), plus one block for the loss sum
#define K3_NORM_BLOCKS (B * S / (256 * 4))   // 8192
__global__ __launch_bounds__(256) void k3_norm(
    float* __restrict__ out,
    const float* __restrict__ mean_arr, const float* __restrict__ rstd_arr,
    const float* __restrict__ smooth_arr)
{
    if ((int)blockIdx.x == K3_NORM_BLOCKS) {
        const int t = threadIdx.x;
        __shared__ float sa[256];
        sa[t] = smooth_arr[t];
        __syncthreads();
        for (int st = 128; st > 0; st >>= 1) {
            if (t < st) sa[t] += sa[t + st];
            __syncthreads();
        }
        if (t == 0) out[B * S] = L2_SMOOTH * sa[0];
        return;
    }

    const int i4   = (int)blockIdx.x * 256 + (int)threadIdx.x;
    const int base = i4 * 4;
    float4 v = *reinterpret_cast<float4*>(&out[base]);
    const int s0 = base & (S - 1);
    v.x = (v.x - mean_arr[s0 + 0]) * rstd_arr[s0 + 0];
    v.y = (v.y - mean_arr[s0 + 1]) * rstd_arr[s0 + 1];
    v.z = (v.z - mean_arr[s0 + 2]) * rstd_arr[s0 + 2];
    v.w = (v.w - mean_arr[s0 + 3]) * rstd_arr[s0 + 3];
    *reinterpret_cast<float4*>(&out[base]) = v;
}

extern "C" void kernel_launch(void* const* d_in, const int* in_sizes, int n_in,
                              void* d_out, int out_size, void* d_ws, size_t ws_size,
                              hipStream_t stream) {
    const float* x  = (const float*)d_in[0];
    const float* W1 = (const float*)d_in[1];
    const float* b1 = (const float*)d_in[2];
    const float* W2 = (const float*)d_in[3];
    const float* b2 = (const float*)d_in[4];
    const float* W3 = (const float*)d_in[5];
    const float* b3 = (const float*)d_in[6];
    float* out = (float*)d_out;

    // ws (floats): psum[S*CH] | psum2[S*CH] | pg2[S*CH] | mean[S] | rstd[S] | smooth[S]
    float* psum   = (float*)d_ws;
    float* psum2  = psum  + S * CH;
    float* pg2    = psum2 + S * CH;
    float* meanA  = pg2   + S * CH;
    float* rstdA  = meanA + S;
    float* smooth = rstdA + S;

    k1_mlp<<<S * CH / WPB, 64 * WPB, 0, stream>>>(
        x, W1, b1, W2, b2, W3, b3, out, psum, psum2, pg2);
    k2_reduce<<<S, 64, 0, stream>>>(psum, psum2, pg2, meanA, rstdA, smooth);
    k3_norm<<<K3_NORM_BLOCKS + 1, 256, 0, stream>>>(out, meanA, rstdA, smooth);
}